// Round 17
// baseline (249.666 us; speedup 1.0000x reference)
//
#include <hip/hip_runtime.h>

#define E_DIM 64
#define N_E   1024
#define N_PTS 32768

// d_out layout (floats):
#define OFF_ZQ   1
#define OFF_PERP 2097153
#define OFF_OH   2097154
#define OFF_IDX  35651586

// d_ws layout (bytes):
#define WS_LOSS    0        // float
#define WS_FIXCNT  4        // uint (unused)
#define WS_COUNTS  256      // uint[1024]
#define WS_NORMS   8192     // float[1024]
#define WS_IDX     16384    // int[32768]        (ends 147456)
#define WS_EBT     311296   // ushort[1024*128]  tile-major B-fragment stream

typedef __attribute__((ext_vector_type(8))) short short8;
typedef __attribute__((ext_vector_type(4))) float f32x4;
typedef __attribute__((ext_vector_type(2))) float f32x2;

// numpy pairwise_sum replication for n=64 over squares (fp32, no contraction)
__device__ __forceinline__ float np_sum64_sq(const float* a) {
#pragma clang fp contract(off)
    float r0 = a[0] * a[0];
    float r1 = a[1] * a[1];
    float r2 = a[2] * a[2];
    float r3 = a[3] * a[3];
    float r4 = a[4] * a[4];
    float r5 = a[5] * a[5];
    float r6 = a[6] * a[6];
    float r7 = a[7] * a[7];
#pragma unroll
    for (int m = 1; m < 8; ++m) {
        r0 += a[8 * m + 0] * a[8 * m + 0];
        r1 += a[8 * m + 1] * a[8 * m + 1];
        r2 += a[8 * m + 2] * a[8 * m + 2];
        r3 += a[8 * m + 3] * a[8 * m + 3];
        r4 += a[8 * m + 4] * a[8 * m + 4];
        r5 += a[8 * m + 5] * a[8 * m + 5];
        r6 += a[8 * m + 6] * a[8 * m + 6];
        r7 += a[8 * m + 7] * a[8 * m + 7];
    }
    return ((r0 + r1) + (r2 + r3)) + ((r4 + r5) + (r6 + r7));
}

__device__ __forceinline__ unsigned short rn_bf16(float f) {
    unsigned int u = __float_as_uint(f);
    return (unsigned short)((u + 0x7FFFu + ((u >> 16) & 1u)) >> 16);
}
__device__ __forceinline__ float bf16_to_f(unsigned short h) {
    return __uint_as_float(((unsigned int)h) << 16);
}

// prep: codebook -> tile-major split-bf16 fragment stream + ||e||^2.
__global__ void eprep_kernel(const float* __restrict__ emb,
                             unsigned short* __restrict__ ebt,
                             float* __restrict__ norms,
                             unsigned int* __restrict__ ws_head,
                             unsigned int* __restrict__ counts) {
    int k = blockIdx.x * blockDim.x + threadIdx.x;
    if (blockIdx.x == 0) {
        if (threadIdx.x < 4) ws_head[threadIdx.x] = 0u;
        *reinterpret_cast<uint4*>(&counts[threadIdx.x * 4]) = make_uint4(0u, 0u, 0u, 0u);
    }
    if (k >= N_E) return;
    float er[E_DIM];
    const float4* e4 = reinterpret_cast<const float4*>(emb) + (size_t)k * (E_DIM / 4);
#pragma unroll
    for (int i = 0; i < E_DIM / 4; ++i)
        *reinterpret_cast<float4*>(&er[i * 4]) = e4[i];
    norms[k] = np_sum64_sq(er);

    unsigned short hi[E_DIM], lo[E_DIM];
#pragma unroll
    for (int c = 0; c < E_DIM; ++c) {
        unsigned short h = rn_bf16(er[c]);
        hi[c] = h;
        lo[c] = rn_bf16(er[c] - bf16_to_f(h));
    }
    const int tile = k >> 4, lc = k & 15;
    short8* dst = reinterpret_cast<short8*>(ebt);
#pragma unroll
    for (int rg = 0; rg < 4; ++rg) {
        short8 f0, f1, f2, f3;
#pragma unroll
        for (int j = 0; j < 8; ++j) {
            f0[j] = (short)hi[rg * 8 + j];
            f1[j] = (short)hi[32 + rg * 8 + j];
            f2[j] = (short)lo[rg * 8 + j];
            f3[j] = (short)lo[32 + rg * 8 + j];
        }
        const int lane = rg * 16 + lc;
        dst[(tile * 4 + 0) * 64 + lane] = f0;
        dst[(tile * 4 + 1) * 64 + lane] = f1;
        dst[(tile * 4 + 2) * 64 + lane] = f2;
        dst[(tile * 4 + 3) * 64 + lane] = f3;
    }
}

// ---------------- kargmin (+inline block-local fix) ----------------
// 1024 blocks x 256 thr (4 waves). Block = 32 points. Wave q owns
// code-quarter q (256 codes, 16 tiles) for ALL 32 points (r16 structure:
// barrier-free K-loop, 4 waves/SIMD TLP, 2x arithmetic intensity).
// Tail: block re-resolves its OWN flagged near-tie rows in fp64
// (r3-validated 256-thread rescan) -> no separate kfix dispatch.
#define LDT(F0, F1, F2, F3, t) {                         \
        const int T_ = q16 + ((t) & 15);                 \
        F0 = ep[(T_ * 4 + 0) * 64];                      \
        F1 = ep[(T_ * 4 + 1) * 64];                      \
        F2 = ep[(T_ * 4 + 2) * 64];                      \
        F3 = ep[(T_ * 4 + 3) * 64];                      \
    }
#define COMP(F0, F1, F2, F3, t) {                                              \
        const int code = q256 + (t) * 16 + lc;                                 \
        const float ne_c = sne[code];                                          \
        _Pragma("unroll")                                                      \
        for (int a = 0; a < 2; ++a) {                                          \
            f32x4 pA  = {0.f, 0.f, 0.f, 0.f};                                  \
            f32x4 pB1 = {0.f, 0.f, 0.f, 0.f};                                  \
            f32x4 pB2 = {0.f, 0.f, 0.f, 0.f};                                  \
            pA  = __builtin_amdgcn_mfma_f32_16x16x32_bf16(zh0[a], F0, pA , 0, 0, 0);\
            pB1 = __builtin_amdgcn_mfma_f32_16x16x32_bf16(zh0[a], F2, pB1, 0, 0, 0);\
            pB2 = __builtin_amdgcn_mfma_f32_16x16x32_bf16(zl0[a], F0, pB2, 0, 0, 0);\
            pA  = __builtin_amdgcn_mfma_f32_16x16x32_bf16(zh1[a], F1, pA , 0, 0, 0);\
            pB1 = __builtin_amdgcn_mfma_f32_16x16x32_bf16(zh1[a], F3, pB1, 0, 0, 0);\
            pB2 = __builtin_amdgcn_mfma_f32_16x16x32_bf16(zl1[a], F1, pB2, 0, 0, 0);\
            _Pragma("unroll")                                                  \
            for (int r = 0; r < 4; ++r) {                                      \
                float t1 = nzr[a][r] + ne_c;                                   \
                float d = fmaf(-2.0f, (pA[r] + pB1[r]) + pB2[r], t1);          \
                float m = fminf(d, b2[a][r]);                                  \
                bool lt = d < b1[a][r];                                        \
                b2[a][r] = lt ? b1[a][r] : m;                                  \
                k1[a][r] = lt ? code : k1[a][r];                               \
                b1[a][r] = fminf(d, b1[a][r]);                                 \
            }                                                                  \
        }                                                                      \
    }

__global__ __launch_bounds__(256, 4) void kargmin_kernel(
    const float* __restrict__ z, const float* __restrict__ emb,
    const unsigned short* __restrict__ ebt, const float* __restrict__ norms,
    int* __restrict__ idx, unsigned int* __restrict__ counts,
    float* __restrict__ out_idx)
{
    __shared__ float szt[32][68];
    __shared__ float snz[32];
    __shared__ float sne[N_E];
    __shared__ float mb1[4][32], mb2[4][32];
    __shared__ int   mk1[4][32];
    __shared__ int   sK[32];
    __shared__ int   sfix[32];
    __shared__ unsigned int sfcnt;
    __shared__ float sd[256];
    __shared__ int   si[256];

    const int tid = threadIdx.x;
    const int wave = tid >> 6;
    const int lane = tid & 63;
    const int lc = lane & 15;
    const int rg = lane >> 4;
    const int q16 = wave * 16;
    const int q256 = wave * 256;
    const int pbase = blockIdx.x * 32;
    const int b = pbase >> 10;
    const int hw0 = pbase & 1023;

    if (tid == 0) sfcnt = 0u;

    // stage z tile: 32 consecutive pts per c -> 128B segments
    {
        const int pt = tid & 31, c0 = tid >> 5;
#pragma unroll
        for (int cg = 0; cg < 8; ++cg) {
            int c = cg * 8 + c0;
            szt[pt][c] = z[((b * E_DIM + c) << 10) + hw0 + pt];
        }
    }
    *reinterpret_cast<float4*>(&sne[tid * 4]) =
        *reinterpret_cast<const float4*>(norms + tid * 4);
    __syncthreads();
    if (tid < 32) snz[tid] = np_sum64_sq(&szt[tid][0]);
    __syncthreads();

    // A-fragments for 2 point-tiles
    short8 zh0[2], zh1[2], zl0[2], zl1[2];
#pragma unroll
    for (int a = 0; a < 2; ++a) {
        const int pa = a * 16 + lc;
        float4 zv0 = *reinterpret_cast<const float4*>(&szt[pa][rg * 8]);
        float4 zv1 = *reinterpret_cast<const float4*>(&szt[pa][rg * 8 + 4]);
        float4 zv2 = *reinterpret_cast<const float4*>(&szt[pa][32 + rg * 8]);
        float4 zv3 = *reinterpret_cast<const float4*>(&szt[pa][32 + rg * 8 + 4]);
        float zt0[8] = {zv0.x, zv0.y, zv0.z, zv0.w, zv1.x, zv1.y, zv1.z, zv1.w};
        float zt1[8] = {zv2.x, zv2.y, zv2.z, zv2.w, zv3.x, zv3.y, zv3.z, zv3.w};
#pragma unroll
        for (int j = 0; j < 8; ++j) {
            unsigned short h0 = rn_bf16(zt0[j]);
            zh0[a][j] = (short)h0;
            zl0[a][j] = (short)rn_bf16(zt0[j] - bf16_to_f(h0));
            unsigned short h1 = rn_bf16(zt1[j]);
            zh1[a][j] = (short)h1;
            zl1[a][j] = (short)rn_bf16(zt1[j] - bf16_to_f(h1));
        }
    }

    float nzr[2][4];
#pragma unroll
    for (int a = 0; a < 2; ++a)
#pragma unroll
        for (int r = 0; r < 4; ++r)
            nzr[a][r] = snz[a * 16 + rg * 4 + r];

    float b1[2][4], b2[2][4];
    int k1[2][4];
#pragma unroll
    for (int a = 0; a < 2; ++a)
#pragma unroll
        for (int r = 0; r < 4; ++r) {
            b1[a][r] = 3.4028235e38f; b2[a][r] = 3.4028235e38f; k1[a][r] = 0;
        }

    const short8* ep = reinterpret_cast<const short8*>(ebt) + lane;

    short8 A0, A1, A2, A3, B0, B1, B2, B3;
    LDT(A0, A1, A2, A3, 0);
    LDT(B0, B1, B2, B3, 1);

#pragma unroll 4
    for (int t = 0; t < 16; t += 2) {
        COMP(A0, A1, A2, A3, t);
        LDT(A0, A1, A2, A3, t + 2);
        COMP(B0, B1, B2, B3, t + 1);
        LDT(B0, B1, B2, B3, t + 3);
    }

    // intra-wave top-2 merge across the 16 code-column lanes
#pragma unroll
    for (int off = 1; off < 16; off <<= 1) {
#pragma unroll
        for (int a = 0; a < 2; ++a)
#pragma unroll
            for (int r = 0; r < 4; ++r) {
                float ob1 = __shfl_xor(b1[a][r], off, 64);
                float ob2 = __shfl_xor(b2[a][r], off, 64);
                int   ok1 = __shfl_xor(k1[a][r], off, 64);
                float nb2 = fminf(fmaxf(b1[a][r], ob1), fminf(b2[a][r], ob2));
                if (ob1 < b1[a][r] || (ob1 == b1[a][r] && ok1 < k1[a][r])) {
                    b1[a][r] = ob1; k1[a][r] = ok1;
                }
                b2[a][r] = nb2;
            }
    }
    if (lc == 0) {
#pragma unroll
        for (int a = 0; a < 2; ++a)
#pragma unroll
            for (int r = 0; r < 4; ++r) {
                mb1[wave][a * 16 + rg * 4 + r] = b1[a][r];
                mb2[wave][a * 16 + rg * 4 + r] = b2[a][r];
                mk1[wave][a * 16 + rg * 4 + r] = k1[a][r];
            }
    }
    __syncthreads();

    // cross-wave (code-quarter) merge + outputs + block-local flag list
    if (tid < 32) {
        const int row = tid;
        float Bb1 = mb1[0][row], Bb2 = mb2[0][row];
        int K = mk1[0][row];
#pragma unroll
        for (int w = 1; w < 4; ++w) {
            float ob1 = mb1[w][row], ob2 = mb2[w][row];
            int ok = mk1[w][row];
            if (ob1 < Bb1 || (ob1 == Bb1 && ok < K)) {
                Bb2 = fminf(Bb1, ob2); Bb1 = ob1; K = ok;
            } else {
                Bb2 = fminf(Bb2, ob1);
            }
        }
        const int p = pbase + row;
        idx[p] = K;
        out_idx[p] = (float)K;
        sK[row] = K;
        atomicAdd(&counts[K], 1u);
        float gap = Bb2 - Bb1;
        if (gap < 3e-5f || (Bb1 >= 128.f && gap < 6.5e-5f)) {
            unsigned int s = atomicAdd(&sfcnt, 1u);   // LDS atomic
            sfix[s] = row;
        }
    }
    __syncthreads();

    // ---- inline fp64 re-resolution of this block's flagged rows ----
    // (r3-validated 256-thread rescan; replicated-fp32-quantized d;
    //  first-index tie-break)
    const unsigned int nf = sfcnt;
    for (unsigned int f = 0; f < nf; ++f) {
        const int row = sfix[f];
        const float nz = snz[row];
        const int t = tid;
        const float* e0 = emb + (size_t)t * E_DIM;
        const float* e1 = e0 + 256 * E_DIM;
        const float* e2 = e1 + 256 * E_DIM;
        const float* e3 = e2 + 256 * E_DIM;
        double a0 = 0.0, a1 = 0.0, a2 = 0.0, a3 = 0.0;
#pragma unroll
        for (int c = 0; c < E_DIM; ++c) {
            const double zv = (double)szt[row][c];
            a0 += (double)e0[c] * zv;
            a1 += (double)e1[c] * zv;
            a2 += (double)e2[c] * zv;
            a3 += (double)e3[c] * zv;
        }
        float d0, d1, d2, d3;
        {
#pragma clang fp contract(off)
            float t0 = nz + sne[t];
            float t1 = nz + sne[t + 256];
            float t2 = nz + sne[t + 512];
            float t3 = nz + sne[t + 768];
            d0 = t0 - 2.0f * (float)a0;
            d1 = t1 - 2.0f * (float)a1;
            d2 = t2 - 2.0f * (float)a2;
            d3 = t3 - 2.0f * (float)a3;
        }
        float best = d0; int bestk = t;                 // ascending k:
        if (d1 < best) { best = d1; bestk = t + 256; }  // strict < keeps
        if (d2 < best) { best = d2; bestk = t + 512; }  // first index
        if (d3 < best) { best = d3; bestk = t + 768; }

        sd[t] = best; si[t] = bestk;
        __syncthreads();
        for (int off = 128; off > 0; off >>= 1) {
            if (t < off) {
                float ob = sd[t + off]; int ok = si[t + off];
                if (ob < sd[t] || (ob == sd[t] && ok < si[t])) {
                    sd[t] = ob; si[t] = ok;
                }
            }
            __syncthreads();
        }
        if (t == 0) {
            const int newk = si[0], oldk = sK[row];
            if (newk != oldk) {
                const int p = pbase + row;
                idx[p] = newk;
                out_idx[p] = (float)newk;
                atomicSub(&counts[oldk], 1u);
                atomicAdd(&counts[newk], 1u);
            }
        }
        __syncthreads();
    }
}

// ---- kzqoh: full one-hot rows (zeros+one, f32x2) + zq gather + loss ----
// 1024 blocks x 256 thr, 32 points each. Dedicated light kernel: low VGPR,
// no fences, plain coalesced stores.
__global__ __launch_bounds__(256) void kzqoh_kernel(
    const float* __restrict__ z, const float* __restrict__ emb,
    const int* __restrict__ idx,
    float* __restrict__ zq_out, float* __restrict__ oh,
    float* __restrict__ loss_accum)
{
    __shared__ float se[32 * 65];
    __shared__ int sk[32];
    __shared__ float wsum[4];

    const int tid = threadIdx.x;
    const int pbase = blockIdx.x * 32;
    const int b = pbase >> 10;
    const int hw0 = pbase & 1023;

    if (tid < 32) sk[tid] = idx[pbase + tid];
    __syncthreads();

    // full one-hot rows: 32 rows x 1024 cols, f32x2 coalesced (base 8B-aligned)
#pragma unroll
    for (int r = 0; r < 32; ++r) {
        const int k = sk[r];
        f32x2* rp = reinterpret_cast<f32x2*>(&oh[(size_t)(pbase + r) * N_E]);
        f32x2 v0 = {(2 * tid == k) ? 1.f : 0.f,
                    (2 * tid + 1 == k) ? 1.f : 0.f};
        f32x2 v1 = {(2 * tid + 512 == k) ? 1.f : 0.f,
                    (2 * tid + 513 == k) ? 1.f : 0.f};
        rp[tid] = v0;
        rp[tid + 256] = v1;
    }

    // stage the 32 selected emb rows (coalesced within rows)
    const float4* emb4 = reinterpret_cast<const float4*>(emb);
#pragma unroll
    for (int i = 0; i < 2; ++i) {
        int fi = tid + i * 256;
        int row = fi >> 4, c4 = fi & 15;
        float4 v = emb4[(size_t)sk[row] * 16 + c4];
        se[row * 65 + c4 * 4 + 0] = v.x;
        se[row * 65 + c4 * 4 + 1] = v.y;
        se[row * 65 + c4 * 4 + 2] = v.z;
        se[row * 65 + c4 * 4 + 3] = v.w;
    }
    __syncthreads();

    // emit z_q (B,C,H,W) + loss partial
    const int p = tid & 31;
    const int cgrp = tid >> 5;           // 0..7, 8 c's each
    float ssum = 0.f;
#pragma unroll
    for (int j = 0; j < 8; ++j) {
        const int c = cgrp * 8 + j;
        const int f = ((b * E_DIM + c) << 10) + hw0 + p;
        float q = se[p * 65 + c];
        float zv = z[f];
        zq_out[f] = q;
        float dd = q - zv;
        ssum += dd * dd;
    }
#pragma unroll
    for (int off = 32; off > 0; off >>= 1) ssum += __shfl_down(ssum, off, 64);
    const int lane = tid & 63, wid = tid >> 6;
    if (lane == 0) wsum[wid] = ssum;
    __syncthreads();
    if (tid == 0)
        atomicAdd(loss_accum, wsum[0] + wsum[1] + wsum[2] + wsum[3]);
}

__global__ void kfin_kernel(const unsigned int* __restrict__ counts,
                            const float* __restrict__ loss_accum,
                            float* __restrict__ out_loss, float* __restrict__ out_perp)
{
    int k = threadIdx.x;
    float em = (float)counts[k] / (float)N_PTS;
    float v = em * logf(em + 1e-10f);
#pragma unroll
    for (int off = 32; off > 0; off >>= 1) v += __shfl_down(v, off, 64);
    __shared__ float sb[16];
    int lane = k & 63, wid = k >> 6;
    if (lane == 0) sb[wid] = v;
    __syncthreads();
    if (k == 0) {
        float ssum = 0.f;
#pragma unroll
        for (int i = 0; i < 16; ++i) ssum += sb[i];
        *out_perp = expf(-ssum);
        *out_loss = 1.25f * (*loss_accum) / 2097152.f;
    }
}

extern "C" void kernel_launch(void* const* d_in, const int* in_sizes, int n_in,
                              void* d_out, int out_size, void* d_ws, size_t ws_size,
                              hipStream_t stream) {
    const float* z   = (const float*)d_in[0];
    const float* emb = (const float*)d_in[1];
    float* out = (float*)d_out;

    float* out_loss = out;
    float* out_zq   = out + OFF_ZQ;
    float* out_perp = out + OFF_PERP;
    float* out_oh   = out + OFF_OH;
    float* out_idx  = out + OFF_IDX;

    char* ws = (char*)d_ws;
    float*          loss_accum = (float*)(ws + WS_LOSS);
    unsigned int*   ws_head    = (unsigned int*)(ws + WS_LOSS);
    unsigned int*   counts     = (unsigned int*)(ws + WS_COUNTS);
    float*          norms      = (float*)(ws + WS_NORMS);
    int*            idx        = (int*)(ws + WS_IDX);
    unsigned short* ebt        = (unsigned short*)(ws + WS_EBT);

    eprep_kernel<<<(N_E + 255) / 256, 256, 0, stream>>>(emb, ebt, norms,
                                                        ws_head, counts);
    kargmin_kernel<<<N_PTS / 32, 256, 0, stream>>>(z, emb, ebt, norms,
                                                   idx, counts, out_idx);
    kzqoh_kernel<<<N_PTS / 32, 256, 0, stream>>>(z, emb, idx, out_zq, out_oh,
                                                 loss_accum);
    kfin_kernel<<<1, 1024, 0, stream>>>(counts, loss_accum, out_loss, out_perp);
}

// Round 18
// 105.447 us; speedup vs baseline: 2.3677x; 2.3677x over previous
//
#include <hip/hip_runtime.h>

#define E_DIM 64
#define N_E   1024
#define N_PTS 32768

// d_out layout (floats):
#define OFF_ZQ   1
#define OFF_PERP 2097153
#define OFF_OH   2097154
#define OFF_IDX  35651586

// d_ws layout (bytes):
#define WS_LOSS    0        // float
#define WS_FIXCNT  4        // uint
#define WS_COUNTS  256      // uint[1024]
#define WS_NORMS   8192     // float[1024]
#define WS_IDX     16384    // int[32768]        (ends 147456)
#define WS_FIXLIST 147456   // int[8192]         (ends 180224)
#define WS_NZ      180224   // float[32768]      (ends 311296)
#define WS_EBT     311296   // ushort[1024*128]  tile-major B-fragment stream
#define FIXCAP     8192

typedef __attribute__((ext_vector_type(8))) short short8;
typedef __attribute__((ext_vector_type(4))) float f32x4;

// numpy pairwise_sum replication for n=64 over squares (fp32, no contraction)
__device__ __forceinline__ float np_sum64_sq(const float* a) {
#pragma clang fp contract(off)
    float r0 = a[0] * a[0];
    float r1 = a[1] * a[1];
    float r2 = a[2] * a[2];
    float r3 = a[3] * a[3];
    float r4 = a[4] * a[4];
    float r5 = a[5] * a[5];
    float r6 = a[6] * a[6];
    float r7 = a[7] * a[7];
#pragma unroll
    for (int m = 1; m < 8; ++m) {
        r0 += a[8 * m + 0] * a[8 * m + 0];
        r1 += a[8 * m + 1] * a[8 * m + 1];
        r2 += a[8 * m + 2] * a[8 * m + 2];
        r3 += a[8 * m + 3] * a[8 * m + 3];
        r4 += a[8 * m + 4] * a[8 * m + 4];
        r5 += a[8 * m + 5] * a[8 * m + 5];
        r6 += a[8 * m + 6] * a[8 * m + 6];
        r7 += a[8 * m + 7] * a[8 * m + 7];
    }
    return ((r0 + r1) + (r2 + r3)) + ((r4 + r5) + (r6 + r7));
}

__device__ __forceinline__ unsigned short rn_bf16(float f) {
    unsigned int u = __float_as_uint(f);
    return (unsigned short)((u + 0x7FFFu + ((u >> 16) & 1u)) >> 16);
}
__device__ __forceinline__ float bf16_to_f(unsigned short h) {
    return __uint_as_float(((unsigned int)h) << 16);
}

// prep: codebook -> tile-major split-bf16 fragment stream + ||e||^2.
__global__ void eprep_kernel(const float* __restrict__ emb,
                             unsigned short* __restrict__ ebt,
                             float* __restrict__ norms,
                             unsigned int* __restrict__ ws_head,
                             unsigned int* __restrict__ counts) {
    int k = blockIdx.x * blockDim.x + threadIdx.x;
    if (blockIdx.x == 0) {
        if (threadIdx.x < 4) ws_head[threadIdx.x] = 0u;
        *reinterpret_cast<uint4*>(&counts[threadIdx.x * 4]) = make_uint4(0u, 0u, 0u, 0u);
    }
    if (k >= N_E) return;
    float er[E_DIM];
    const float4* e4 = reinterpret_cast<const float4*>(emb) + (size_t)k * (E_DIM / 4);
#pragma unroll
    for (int i = 0; i < E_DIM / 4; ++i)
        *reinterpret_cast<float4*>(&er[i * 4]) = e4[i];
    norms[k] = np_sum64_sq(er);

    unsigned short hi[E_DIM], lo[E_DIM];
#pragma unroll
    for (int c = 0; c < E_DIM; ++c) {
        unsigned short h = rn_bf16(er[c]);
        hi[c] = h;
        lo[c] = rn_bf16(er[c] - bf16_to_f(h));
    }
    const int tile = k >> 4, lc = k & 15;
    short8* dst = reinterpret_cast<short8*>(ebt);
#pragma unroll
    for (int rg = 0; rg < 4; ++rg) {
        short8 f0, f1, f2, f3;
#pragma unroll
        for (int j = 0; j < 8; ++j) {
            f0[j] = (short)hi[rg * 8 + j];
            f1[j] = (short)hi[32 + rg * 8 + j];
            f2[j] = (short)lo[rg * 8 + j];
            f3[j] = (short)lo[32 + rg * 8 + j];
        }
        const int lane = rg * 16 + lc;
        dst[(tile * 4 + 0) * 64 + lane] = f0;
        dst[(tile * 4 + 1) * 64 + lane] = f1;
        dst[(tile * 4 + 2) * 64 + lane] = f2;
        dst[(tile * 4 + 3) * 64 + lane] = f3;
    }
}

// ---------------- kargmin: 1024 blocks x 256 thr (4 waves) ----------------
// Block = 32 points. Wave q owns code-quarter q (256 codes, 16 tiles) for
// ALL 32 points (two A-tiles a=0/1). Barrier-free K-loop, 4 waves/SIMD TLP.
#define LDT(F0, F1, F2, F3, t) {                         \
        const int T_ = q16 + ((t) & 15);                 \
        F0 = ep[(T_ * 4 + 0) * 64];                      \
        F1 = ep[(T_ * 4 + 1) * 64];                      \
        F2 = ep[(T_ * 4 + 2) * 64];                      \
        F3 = ep[(T_ * 4 + 3) * 64];                      \
    }
#define COMP(F0, F1, F2, F3, t) {                                              \
        const int code = q256 + (t) * 16 + lc;                                 \
        const float ne_c = sne[code];                                          \
        _Pragma("unroll")                                                      \
        for (int a = 0; a < 2; ++a) {                                          \
            f32x4 pA  = {0.f, 0.f, 0.f, 0.f};                                  \
            f32x4 pB1 = {0.f, 0.f, 0.f, 0.f};                                  \
            f32x4 pB2 = {0.f, 0.f, 0.f, 0.f};                                  \
            pA  = __builtin_amdgcn_mfma_f32_16x16x32_bf16(zh0[a], F0, pA , 0, 0, 0);\
            pB1 = __builtin_amdgcn_mfma_f32_16x16x32_bf16(zh0[a], F2, pB1, 0, 0, 0);\
            pB2 = __builtin_amdgcn_mfma_f32_16x16x32_bf16(zl0[a], F0, pB2, 0, 0, 0);\
            pA  = __builtin_amdgcn_mfma_f32_16x16x32_bf16(zh1[a], F1, pA , 0, 0, 0);\
            pB1 = __builtin_amdgcn_mfma_f32_16x16x32_bf16(zh1[a], F3, pB1, 0, 0, 0);\
            pB2 = __builtin_amdgcn_mfma_f32_16x16x32_bf16(zl1[a], F1, pB2, 0, 0, 0);\
            _Pragma("unroll")                                                  \
            for (int r = 0; r < 4; ++r) {                                      \
                float t1 = nzr[a][r] + ne_c;                                   \
                float d = fmaf(-2.0f, (pA[r] + pB1[r]) + pB2[r], t1);          \
                float m = fminf(d, b2[a][r]);                                  \
                bool lt = d < b1[a][r];                                        \
                b2[a][r] = lt ? b1[a][r] : m;                                  \
                k1[a][r] = lt ? code : k1[a][r];                               \
                b1[a][r] = fminf(d, b1[a][r]);                                 \
            }                                                                  \
        }                                                                      \
    }

__global__ __launch_bounds__(256, 4) void kargmin_kernel(
    const float* __restrict__ z, const unsigned short* __restrict__ ebt,
    const float* __restrict__ norms,
    int* __restrict__ idx, unsigned int* __restrict__ counts,
    float* __restrict__ out_idx, float* __restrict__ nzG,
    unsigned int* __restrict__ fixcnt, int* __restrict__ fixlist)
{
    __shared__ float szt[32][68];
    __shared__ float snz[32];
    __shared__ float sne[N_E];
    __shared__ float mb1[4][32], mb2[4][32];
    __shared__ int   mk1[4][32];

    const int tid = threadIdx.x;
    const int wave = tid >> 6;
    const int lane = tid & 63;
    const int lc = lane & 15;
    const int rg = lane >> 4;
    const int q16 = wave * 16;      // tile base of this wave's code-quarter
    const int q256 = wave * 256;    // code base
    const int pbase = blockIdx.x * 32;
    const int b = pbase >> 10;
    const int hw0 = pbase & 1023;

    // stage z tile: 32 consecutive pts per c -> 128B segments (256 thr)
    {
        const int pt = tid & 31, c0 = tid >> 5;
#pragma unroll
        for (int cg = 0; cg < 8; ++cg) {
            int c = cg * 8 + c0;
            szt[pt][c] = z[((b * E_DIM + c) << 10) + hw0 + pt];
        }
    }
    *reinterpret_cast<float4*>(&sne[tid * 4]) =
        *reinterpret_cast<const float4*>(norms + tid * 4);
    __syncthreads();
    if (tid < 32) {
        float v = np_sum64_sq(&szt[tid][0]);
        snz[tid] = v;
        nzG[pbase + tid] = v;
    }
    __syncthreads();

    // A-fragments for 2 point-tiles (a=0: pts 0-15, a=1: pts 16-31)
    short8 zh0[2], zh1[2], zl0[2], zl1[2];
#pragma unroll
    for (int a = 0; a < 2; ++a) {
        const int pa = a * 16 + lc;
        float4 zv0 = *reinterpret_cast<const float4*>(&szt[pa][rg * 8]);
        float4 zv1 = *reinterpret_cast<const float4*>(&szt[pa][rg * 8 + 4]);
        float4 zv2 = *reinterpret_cast<const float4*>(&szt[pa][32 + rg * 8]);
        float4 zv3 = *reinterpret_cast<const float4*>(&szt[pa][32 + rg * 8 + 4]);
        float zt0[8] = {zv0.x, zv0.y, zv0.z, zv0.w, zv1.x, zv1.y, zv1.z, zv1.w};
        float zt1[8] = {zv2.x, zv2.y, zv2.z, zv2.w, zv3.x, zv3.y, zv3.z, zv3.w};
#pragma unroll
        for (int j = 0; j < 8; ++j) {
            unsigned short h0 = rn_bf16(zt0[j]);
            zh0[a][j] = (short)h0;
            zl0[a][j] = (short)rn_bf16(zt0[j] - bf16_to_f(h0));
            unsigned short h1 = rn_bf16(zt1[j]);
            zh1[a][j] = (short)h1;
            zl1[a][j] = (short)rn_bf16(zt1[j] - bf16_to_f(h1));
        }
    }

    float nzr[2][4];
#pragma unroll
    for (int a = 0; a < 2; ++a)
#pragma unroll
        for (int r = 0; r < 4; ++r)
            nzr[a][r] = snz[a * 16 + rg * 4 + r];

    float b1[2][4], b2[2][4];
    int k1[2][4];
#pragma unroll
    for (int a = 0; a < 2; ++a)
#pragma unroll
        for (int r = 0; r < 4; ++r) {
            b1[a][r] = 3.4028235e38f; b2[a][r] = 3.4028235e38f; k1[a][r] = 0;
        }

    // per-lane fragment-stream pointer
    const short8* ep = reinterpret_cast<const short8*>(ebt) + lane;

    short8 A0, A1, A2, A3, B0, B1, B2, B3;
    LDT(A0, A1, A2, A3, 0);
    LDT(B0, B1, B2, B3, 1);

#pragma unroll 4
    for (int t = 0; t < 16; t += 2) {
        COMP(A0, A1, A2, A3, t);
        LDT(A0, A1, A2, A3, t + 2);
        COMP(B0, B1, B2, B3, t + 1);
        LDT(B0, B1, B2, B3, t + 3);
    }

    // intra-wave top-2 merge across the 16 code-column lanes
#pragma unroll
    for (int off = 1; off < 16; off <<= 1) {
#pragma unroll
        for (int a = 0; a < 2; ++a)
#pragma unroll
            for (int r = 0; r < 4; ++r) {
                float ob1 = __shfl_xor(b1[a][r], off, 64);
                float ob2 = __shfl_xor(b2[a][r], off, 64);
                int   ok1 = __shfl_xor(k1[a][r], off, 64);
                float nb2 = fminf(fmaxf(b1[a][r], ob1), fminf(b2[a][r], ob2));
                if (ob1 < b1[a][r] || (ob1 == b1[a][r] && ok1 < k1[a][r])) {
                    b1[a][r] = ob1; k1[a][r] = ok1;
                }
                b2[a][r] = nb2;
            }
    }
    if (lc == 0) {
#pragma unroll
        for (int a = 0; a < 2; ++a)
#pragma unroll
            for (int r = 0; r < 4; ++r) {
                mb1[wave][a * 16 + rg * 4 + r] = b1[a][r];
                mb2[wave][a * 16 + rg * 4 + r] = b2[a][r];
                mk1[wave][a * 16 + rg * 4 + r] = k1[a][r];
            }
    }
    __syncthreads();

    // cross-wave (code-quarter) merge + outputs: one thread per point row.
    if (tid < 32) {
        const int row = tid;
        float Bb1 = mb1[0][row], Bb2 = mb2[0][row];
        int K = mk1[0][row];
#pragma unroll
        for (int w = 1; w < 4; ++w) {
            float ob1 = mb1[w][row], ob2 = mb2[w][row];
            int ok = mk1[w][row];
            if (ob1 < Bb1 || (ob1 == Bb1 && ok < K)) {
                Bb2 = fminf(Bb1, ob2); Bb1 = ob1; K = ok;
            } else {
                Bb2 = fminf(Bb2, ob1);
            }
        }
        const int p = pbase + row;
        idx[p] = K;
        out_idx[p] = (float)K;
        atomicAdd(&counts[K], 1u);
        float gap = Bb2 - Bb1;
        if (gap < 3e-5f || (Bb1 >= 128.f && gap < 6.5e-5f)) {
            unsigned int slot = atomicAdd(fixcnt, 1u);
            if (slot < FIXCAP) fixlist[slot] = p;
        }
    }
}

// ---------------- kfix: wave-per-flagged-point, coalesced fp64 ----------------
__global__ __launch_bounds__(256) void kfix_kernel(
    const float* __restrict__ z, const float* __restrict__ emb,
    const float* __restrict__ norms, const float* __restrict__ nzG,
    int* __restrict__ idx, unsigned int* __restrict__ counts,
    float* __restrict__ out_idx,
    const unsigned int* __restrict__ fixcnt,
    const int* __restrict__ fixlist)
{
    unsigned int n = *fixcnt;
    if (n > FIXCAP) n = FIXCAP;
    const int lane = threadIdx.x & 63;
    const int kk = lane & 15;
    const int cg = lane >> 4;
    const unsigned int slot = blockIdx.x * 4 + (threadIdx.x >> 6);

    for (unsigned int it = slot; it < n; it += 4096) {
        const int p = fixlist[it];
        const int b = p >> 10, hw = p & 1023;
        double zc[16];
#pragma unroll
        for (int j = 0; j < 16; ++j)
            zc[j] = (double)z[((b * E_DIM + cg * 16 + j) << 10) + hw];
        const float nz = nzG[p];

        float best = 3.4028235e38f;
        int bestk = 0;
        for (int batch = 0; batch < 64; ++batch) {
            const int k = batch * 16 + kk;
            const float4* er = reinterpret_cast<const float4*>(
                emb + (size_t)k * E_DIM + cg * 16);
            double acc = 0.0;
#pragma unroll
            for (int i = 0; i < 4; ++i) {
                float4 ev = er[i];
                acc += (double)ev.x * zc[i * 4 + 0];
                acc += (double)ev.y * zc[i * 4 + 1];
                acc += (double)ev.z * zc[i * 4 + 2];
                acc += (double)ev.w * zc[i * 4 + 3];
            }
            acc += __shfl_xor(acc, 16, 64);
            acc += __shfl_xor(acc, 32, 64);
            float dotf = (float)acc;
            float d;
            {
#pragma clang fp contract(off)
                float t1 = nz + norms[k];
                d = t1 - 2.0f * dotf;
            }
            if (d < best) { best = d; bestk = k; }
        }
#pragma unroll
        for (int off = 1; off < 16; off <<= 1) {
            float ob = __shfl_xor(best, off, 64);
            int   ok = __shfl_xor(bestk, off, 64);
            if (ob < best || (ob == best && ok < bestk)) { best = ob; bestk = ok; }
        }
        if (lane == 0) {
            int oldk = idx[p];
            if (bestk != oldk) {
                idx[p] = bestk;
                out_idx[p] = (float)bestk;
                atomicSub(&counts[oldk], 1u);
                atomicAdd(&counts[bestk], 1u);
            }
        }
    }
}

// ---- kzq: LDS-transpose gather + fused loss + one-hot ones (plain stores) ----
__global__ __launch_bounds__(256) void kzq_kernel(
    const float* __restrict__ z, const float* __restrict__ emb,
    const int* __restrict__ idx,
    float* __restrict__ zq_out, float* __restrict__ oh,
    float* __restrict__ loss_accum)
{
    __shared__ float se[64 * 65];
    __shared__ int sk[64];
    __shared__ float wsum[4];

    const int tid = threadIdx.x;
    const int pbase = blockIdx.x * 64;
    const int b = pbase >> 10;
    const int hw0 = pbase & 1023;

    if (tid < 64) sk[tid] = idx[pbase + tid];
    __syncthreads();

    if (tid < 64)
        oh[(size_t)(pbase + tid) * N_E + sk[tid]] = 1.0f;

    const float4* emb4 = reinterpret_cast<const float4*>(emb);
#pragma unroll
    for (int i = 0; i < 4; ++i) {
        int fi = tid + i * 256;
        int row = fi >> 4, c4 = fi & 15;
        float4 v = emb4[(size_t)sk[row] * 16 + c4];
        se[row * 65 + c4 * 4 + 0] = v.x;
        se[row * 65 + c4 * 4 + 1] = v.y;
        se[row * 65 + c4 * 4 + 2] = v.z;
        se[row * 65 + c4 * 4 + 3] = v.w;
    }
    __syncthreads();

    const int p = tid & 63;
    const int cgrp = tid >> 6;
    float ssum = 0.f;
#pragma unroll
    for (int j = 0; j < 16; ++j) {
        const int c = cgrp * 16 + j;
        const int f = ((b * E_DIM + c) << 10) + hw0 + p;
        float q = se[p * 65 + c];
        float zv = z[f];
        zq_out[f] = q;
        float dd = q - zv;
        ssum += dd * dd;
    }
#pragma unroll
    for (int off = 32; off > 0; off >>= 1) ssum += __shfl_down(ssum, off, 64);
    const int lane = tid & 63, wid = tid >> 6;
    if (lane == 0) wsum[wid] = ssum;
    __syncthreads();
    if (tid == 0)
        atomicAdd(loss_accum, wsum[0] + wsum[1] + wsum[2] + wsum[3]);
}

__global__ void kfin_kernel(const unsigned int* __restrict__ counts,
                            const float* __restrict__ loss_accum,
                            float* __restrict__ out_loss, float* __restrict__ out_perp)
{
    int k = threadIdx.x;
    float em = (float)counts[k] / (float)N_PTS;
    float v = em * logf(em + 1e-10f);
#pragma unroll
    for (int off = 32; off > 0; off >>= 1) v += __shfl_down(v, off, 64);
    __shared__ float sb[16];
    int lane = k & 63, wid = k >> 6;
    if (lane == 0) sb[wid] = v;
    __syncthreads();
    if (k == 0) {
        float ssum = 0.f;
#pragma unroll
        for (int i = 0; i < 16; ++i) ssum += sb[i];
        *out_perp = expf(-ssum);
        *out_loss = 1.25f * (*loss_accum) / 2097152.f;
    }
}

extern "C" void kernel_launch(void* const* d_in, const int* in_sizes, int n_in,
                              void* d_out, int out_size, void* d_ws, size_t ws_size,
                              hipStream_t stream) {
    const float* z   = (const float*)d_in[0];
    const float* emb = (const float*)d_in[1];
    float* out = (float*)d_out;

    float* out_loss = out;
    float* out_zq   = out + OFF_ZQ;
    float* out_perp = out + OFF_PERP;
    float* out_oh   = out + OFF_OH;
    float* out_idx  = out + OFF_IDX;

    char* ws = (char*)d_ws;
    float*          loss_accum = (float*)(ws + WS_LOSS);
    unsigned int*   ws_head    = (unsigned int*)(ws + WS_LOSS);
    unsigned int*   fixcnt     = (unsigned int*)(ws + WS_FIXCNT);
    unsigned int*   counts     = (unsigned int*)(ws + WS_COUNTS);
    float*          norms      = (float*)(ws + WS_NORMS);
    int*            idx        = (int*)(ws + WS_IDX);
    int*            fixlist    = (int*)(ws + WS_FIXLIST);
    float*          nzG        = (float*)(ws + WS_NZ);
    unsigned short* ebt        = (unsigned short*)(ws + WS_EBT);

    // one-hot zero-fill at fill-primitive speed (~6.5 TB/s measured)
    hipMemsetAsync(out_oh, 0, (size_t)N_PTS * N_E * sizeof(float), stream);

    eprep_kernel<<<(N_E + 255) / 256, 256, 0, stream>>>(emb, ebt, norms,
                                                        ws_head, counts);
    kargmin_kernel<<<N_PTS / 32, 256, 0, stream>>>(z, ebt, norms, idx, counts,
                                                   out_idx, nzG, fixcnt, fixlist);
    kfix_kernel<<<1024, 256, 0, stream>>>(z, emb, norms, nzG, idx, counts,
                                          out_idx, fixcnt, fixlist);
    kzq_kernel<<<N_PTS / 64, 256, 0, stream>>>(z, emb, idx, out_zq, out_oh,
                                               loss_accum);
    kfin_kernel<<<1, 1024, 0, stream>>>(counts, loss_accum, out_loss, out_perp);
}